// Round 4
// baseline (200.418 us; speedup 1.0000x reference)
//
#include <hip/hip_runtime.h>
#include <math.h>

// Problem constants
#define NB 32
#define CI 64
#define CO 64
#define CA 16
#define NK 4
#define HH 128
#define WW 128
#define EPSBN 1e-5f

typedef __bf16 bf16x8 __attribute__((ext_vector_type(8)));
typedef float f32x16 __attribute__((ext_vector_type(16)));

__device__ inline unsigned short f2bf(float f) {
    union { float f; unsigned u; } c; c.f = f;
    return (unsigned short)((c.u + 0x7fffu + ((c.u >> 16) & 1u)) >> 16);
}

// ---- new-path workspace layout (float offsets) ----
#define WS_POOLED 0              // 2048
#define WS_CHA    2048           // 2048
#define WS_FA     4096           // 2048
#define WS_KA     6144           // 128
#define WS_SP     6272           // 288
#define WS_PART   8192           // 32*64*128 = 262144
#define WS_W2T_N  270336         // 1179648 ushorts = 589824 float slots
#define WS_XT     860160         // 33554432 ushorts = 16777216 float slots
#define WS_NEED_F 17637376ull    // floats needed for new path
// ---- fallback layout (r3) ----
#define WS_W2T_F  8192

// ===========================================================================
// A) convert+pool: x[b][ci][h][w] f32 -> xt[b][h][w][ci] bf16, + row sums
//    partial[b][ci][h]. Block = (h, b), 256 threads.
// ===========================================================================
__global__ __launch_bounds__(256) void convert_pool(const float* __restrict__ x,
                                                    unsigned short* __restrict__ xt,
                                                    float* __restrict__ partial) {
    __shared__ unsigned tlds[128 * 36];     // [w][ci-pair], pad 36 for banks/align
    __shared__ float red[64 * 9];           // [ci][q]
    const int tid = threadIdx.x;
    const int p = tid & 31;                  // ci pair
    const int q = tid >> 5;                  // w window (16 wide)
    const int h = blockIdx.x;
    const int b = blockIdx.y;

    const float4* r0 = (const float4*)(x + ((size_t)(b * CI + 2 * p) * HH + h) * WW + q * 16);
    const float4* r1 = (const float4*)((const float*)r0 + HH * WW);
    float a0[16], a1[16];
    #pragma unroll
    for (int j = 0; j < 4; ++j) {
        float4 va = r0[j], vb = r1[j];
        a0[4*j+0]=va.x; a0[4*j+1]=va.y; a0[4*j+2]=va.z; a0[4*j+3]=va.w;
        a1[4*j+0]=vb.x; a1[4*j+1]=vb.y; a1[4*j+2]=vb.z; a1[4*j+3]=vb.w;
    }
    float s0 = 0.f, s1 = 0.f;
    #pragma unroll
    for (int e = 0; e < 16; ++e) {
        s0 += a0[e]; s1 += a1[e];
        tlds[(q * 16 + e) * 36 + p] = (unsigned)f2bf(a0[e]) | ((unsigned)f2bf(a1[e]) << 16);
    }
    red[(2 * p) * 9 + q] = s0;
    red[(2 * p + 1) * 9 + q] = s1;
    __syncthreads();

    // write xt: thread -> 64B contiguous
    {
        const int w = tid >> 1, half = tid & 1;
        const unsigned* src = tlds + w * 36 + half * 16;
        uint4* dst = (uint4*)((unsigned*)xt + ((size_t)(b * HH + h) * WW + w) * 32 + half * 16);
        #pragma unroll
        for (int j = 0; j < 4; ++j) dst[j] = ((const uint4*)src)[j];
    }
    if (tid < 64) {
        float s = 0.f;
        #pragma unroll
        for (int qq = 0; qq < 8; ++qq) s += red[tid * 9 + qq];
        partial[((size_t)b * CI + tid) * HH + h] = s;
    }
}

// B) reduce partial over h -> pooled (sums; scaled later)
__global__ void pool2_kernel(const float* __restrict__ partial, float* __restrict__ pooled) {
    const int g = blockIdx.x * 256 + threadIdx.x;   // 2048
    const float4* p4 = (const float4*)(partial + (size_t)g * HH);
    float s = 0.f;
    #pragma unroll
    for (int j = 0; j < 32; ++j) { float4 v = p4[j]; s += v.x + v.y + v.z + v.w; }
    pooled[g] = s;
}

// ===========================================================================
// fallback pool (means directly)
// ===========================================================================
__global__ void pool_kernel(const float* __restrict__ x, float* __restrict__ pooled) {
    const int plane = blockIdx.x;
    const float4* p = (const float4*)(x + (size_t)plane * (HH * WW));
    float s = 0.f;
    for (int j = threadIdx.x; j < (HH * WW) / 4; j += 256) {
        float4 v = p[j];
        s += v.x + v.y + v.z + v.w;
    }
    #pragma unroll
    for (int off = 32; off > 0; off >>= 1) s += __shfl_down(s, off);
    __shared__ float red[4];
    if ((threadIdx.x & 63) == 0) red[threadIdx.x >> 6] = s;
    __syncthreads();
    if (threadIdx.x == 0)
        pooled[plane] = (red[0] + red[1] + red[2] + red[3]) * (1.f / (HH * WW));
}

// ===========================================================================
// C) attention trunk + heads; pooled entries are scaled by `scale`
// ===========================================================================
__global__ __launch_bounds__(512) void attn2_kernel(
    const float* __restrict__ pooled, const float* __restrict__ prep_w,
    const float* __restrict__ bn_g, const float* __restrict__ bn_b,
    const float* __restrict__ bn_m, const float* __restrict__ bn_v,
    const float* __restrict__ fc_sp_w, const float* __restrict__ fc_sp_b,
    const float* __restrict__ fc_ch_w, const float* __restrict__ fc_ch_b,
    const float* __restrict__ fc_f_w,  const float* __restrict__ fc_f_b,
    const float* __restrict__ fc_k_w,  const float* __restrict__ fc_k_b,
    float* __restrict__ sp, float* __restrict__ cha,
    float* __restrict__ fa, float* __restrict__ ka, float scale) {
    __shared__ float att_s[NB * CA];
    const int tid = threadIdx.x;
    const int b = tid >> 4, a = tid & 15;
    {
        const float4* pv = (const float4*)(pooled + b * CI);
        const float4* wv = (const float4*)(prep_w + a * CI);
        float s = 0.f;
        #pragma unroll
        for (int i = 0; i < 16; ++i) {
            float4 p = pv[i], w = wv[i];
            s += p.x * w.x + p.y * w.y + p.z * w.z + p.w * w.w;
        }
        s = (s * scale - bn_m[a]) * rsqrtf(bn_v[a] + EPSBN) * bn_g[a] + bn_b[a];
        att_s[b * CA + a] = fmaxf(s, 0.f);
    }
    __syncthreads();
    float av[CA];
    #pragma unroll
    for (int i = 0; i < CA; ++i) av[i] = att_s[b * CA + i];

    const int j = a;
    if (j < 9) {
        float s = fc_sp_b[j];
        #pragma unroll
        for (int i = 0; i < CA; ++i) s += av[i] * fc_sp_w[j * CA + i];
        sp[b * 9 + j] = 1.f / (1.f + expf(-s));
    }
    #pragma unroll
    for (int t = 0; t < 4; ++t) {
        const int c = j * 4 + t;
        float s1 = fc_ch_b[c], s2 = fc_f_b[c];
        #pragma unroll
        for (int i = 0; i < CA; ++i) {
            s1 += av[i] * fc_ch_w[c * CA + i];
            s2 += av[i] * fc_f_w[c * CA + i];
        }
        cha[b * CI + c] = 1.f / (1.f + expf(-s1));
        fa[b * CO + c]  = 1.f / (1.f + expf(-s2));
    }
    if (j == 0) {
        float kv[NK], m = -1e30f;
        #pragma unroll
        for (int k = 0; k < NK; ++k) {
            float s = fc_k_b[k];
            #pragma unroll
            for (int i = 0; i < CA; ++i) s += av[i] * fc_k_w[k * CA + i];
            kv[k] = s; m = fmaxf(m, s);
        }
        float den = 0.f;
        #pragma unroll
        for (int k = 0; k < NK; ++k) { kv[k] = expf(kv[k] - m); den += kv[k]; }
        #pragma unroll
        for (int k = 0; k < NK; ++k) ka[b * NK + k] = kv[k] / den;
    }
}

// ===========================================================================
// D) folded weights: w2t[b][tap][o][i] bf16
// ===========================================================================
__global__ void w2t_kernel(const float* __restrict__ kernels,
                           const float* __restrict__ sp, const float* __restrict__ cha,
                           const float* __restrict__ fa, const float* __restrict__ ka,
                           unsigned short* __restrict__ w2t) {
    const int idx = blockIdx.x * 256 + threadIdx.x;    // 1179648 exact
    const int i   = idx & 63;
    const int o   = (idx >> 6) & 63;
    const int tap = (idx >> 12) % 9;
    const int b   = idx / (9 * 4096);
    float s = 0.f;
    #pragma unroll
    for (int k = 0; k < NK; ++k)
        s += ka[b * NK + k] * kernels[((k * CO + o) * CI + i) * 9 + tap];
    w2t[idx] = f2bf(s * sp[b * 9 + tap] * cha[b * CI + i] * fa[b * CO + o]);
}

// ===========================================================================
// E) LDS-free conv: wave = (b, hg, colg, cohalf), 32co x 32cols x 4h.
//    B frags stream from NHWC-bf16 xt (L2/L3-hot), A from w2t. No barriers.
// ===========================================================================
__global__ __launch_bounds__(256, 3) void conv_mfma3(
    const unsigned short* __restrict__ xt, const unsigned short* __restrict__ w2t,
    float* __restrict__ out) {
    const int orig = blockIdx.x;
    const int bid  = (orig & 7) * 256 + (orig >> 3);        // XCD swizzle (bijective)
    const int gw   = bid * 4 + (threadIdx.x >> 6);
    const int b      = gw >> 8;
    const int hg     = (gw >> 3) & 31;
    const int colg   = (gw >> 1) & 3;
    const int cohalf = gw & 1;
    const int h0 = hg * 4;
    const int w0 = colg * 32;
    const int lane = threadIdx.x & 63;
    const int n  = lane & 31;
    const int kh = lane >> 5;

    const unsigned short* wbase = w2t + (size_t)b * (9 * 4096)
                                + (size_t)(cohalf * 32 + n) * 64 + kh * 8;
    const unsigned short* xb = xt + (size_t)b * (HH * WW * CI);

    union ZU { uint4 u; bf16x8 v; };
    ZU zz; zz.u = make_uint4(0u, 0u, 0u, 0u);

    f32x16 acc[4];
    #pragma unroll
    for (int t = 0; t < 4; ++t)
        #pragma unroll
        for (int e = 0; e < 16; ++e) acc[t][e] = 0.f;

    #pragma unroll 1
    for (int ks = 0; ks < 4; ++ks) {
        const int k0 = ks * 16 + kh * 8;
        #pragma unroll
        for (int v = 0; v < 3; ++v) {
            const int cc = w0 + n + v - 1;
            const bool cok = (unsigned)cc < (unsigned)WW;
            const unsigned short* colp = xb + (size_t)cc * CI + k0;
            bf16x8 Bf[6];
            #pragma unroll
            for (int r = 0; r < 6; ++r) {
                const int rr = h0 - 1 + r;
                bf16x8 z = zz.v;
                if (cok && (unsigned)rr < (unsigned)HH)
                    z = *(const bf16x8*)(colp + (size_t)rr * (WW * CI));
                Bf[r] = z;
            }
            const bf16x8 A0 = *(const bf16x8*)(wbase + (0 + v) * 4096 + ks * 16);
            const bf16x8 A1 = *(const bf16x8*)(wbase + (3 + v) * 4096 + ks * 16);
            const bf16x8 A2 = *(const bf16x8*)(wbase + (6 + v) * 4096 + ks * 16);
            #pragma unroll
            for (int t = 0; t < 4; ++t)
                acc[t] = __builtin_amdgcn_mfma_f32_32x32x16_bf16(A0, Bf[t], acc[t], 0, 0, 0);
            #pragma unroll
            for (int t = 0; t < 4; ++t)
                acc[t] = __builtin_amdgcn_mfma_f32_32x32x16_bf16(A1, Bf[t + 1], acc[t], 0, 0, 0);
            #pragma unroll
            for (int t = 0; t < 4; ++t)
                acc[t] = __builtin_amdgcn_mfma_f32_32x32x16_bf16(A2, Bf[t + 2], acc[t], 0, 0, 0);
        }
    }

    #pragma unroll
    for (int t = 0; t < 4; ++t) {
        const int h = h0 + t;
        float* op = out + ((size_t)(b * CO + cohalf * 32) * HH + h) * WW + w0 + n;
        #pragma unroll
        for (int reg = 0; reg < 16; ++reg) {
            const int m = (reg & 3) + 8 * (reg >> 2) + 4 * kh;
            op[(size_t)m * (HH * WW)] = acc[t][reg];
        }
    }
}

// ===========================================================================
// Fallback conv (r3): LDS double-buffered, 64co x 8r x 64c
// ===========================================================================
#define NCOL 66
#define BUFB (10 * NCOL * 32)

__global__ __launch_bounds__(512, 2) void conv_mfma2(
    const float* __restrict__ x, const unsigned short* __restrict__ w2t,
    float* __restrict__ out) {
    __shared__ __align__(16) unsigned char xs[2 * BUFB];

    const int tid  = threadIdx.x;
    const int lane = tid & 63;
    const int wave = tid >> 6;
    const int n    = lane & 31;
    const int kh   = lane >> 5;
    const int cohalf = wave & 1;
    const int rp     = wave >> 1;
    const int w0 = blockIdx.x * 64;
    const int h0 = blockIdx.y * 8;
    const int b  = blockIdx.z;

    const bool sact = tid < 400;
    const int sp_ = tid & 7;
    const int srl = (tid >> 3) & 1;
    const int t4  = tid >> 4;
    const int sq  = t4 % 5;
    const int srh = t4 / 5;
    const int sr  = srh * 2 + srl;
    const int shh = h0 - 1 + sr;
    const bool shok = sact && (unsigned)shh < (unsigned)HH;
    const int wq = w0 - 4 + 16 * sq;

    float4 La[4], Lb[4];
    f32x16 acc[2][2];
    #pragma unroll
    for (int rs = 0; rs < 2; ++rs)
        #pragma unroll
        for (int g = 0; g < 2; ++g)
            #pragma unroll
            for (int q = 0; q < 16; ++q) acc[rs][g][q] = 0.f;

    const unsigned short* w2base = w2t + (size_t)b * 9 * 4096
                                 + (size_t)(cohalf * 32 + n) * 64 + kh * 8;

    auto LOADS = [&](int cnk) {
        #pragma unroll
        for (int jj = 0; jj < 4; ++jj) {
            La[jj] = make_float4(0.f, 0.f, 0.f, 0.f);
            Lb[jj] = make_float4(0.f, 0.f, 0.f, 0.f);
        }
        if (shok) {
            const float* s0 = x + ((size_t)(b * CI + cnk * 16 + 2 * sp_) * HH + shh) * WW;
            const float* s1 = s0 + HH * WW;
            #pragma unroll
            for (int jj = 0; jj < 4; ++jj) {
                const int w = wq + 4 * jj;
                if ((unsigned)w <= 124u) {
                    La[jj] = *(const float4*)(s0 + w);
                    Lb[jj] = *(const float4*)(s1 + w);
                }
            }
        }
    };
    auto WRITE = [&](int cnk) {
        if (sact) {
            unsigned char* dbuf = xs + (cnk & 1) * BUFB;
            const float* la = (const float*)La;
            const float* lb = (const float*)Lb;
            #pragma unroll
            for (int e = 0; e < 16; ++e) {
                const int c = 16 * sq - 3 + e;
                if ((unsigned)c < (unsigned)NCOL) {
                    const unsigned v = (unsigned)f2bf(la[e]) | ((unsigned)f2bf(lb[e]) << 16);
                    *(unsigned*)(dbuf + (sr * NCOL + c) * 32 + ((4 * sp_) ^ ((c & 1) << 4))) = v;
                }
            }
        }
    };
    auto COMPUTE = [&](int cnk) {
        const unsigned char* rb = xs + (cnk & 1) * BUFB;
        const unsigned short* wb = w2base + cnk * 16;
        #pragma unroll
        for (int v = 0; v < 3; ++v) {
            const bf16x8 Af0 = *(const bf16x8*)(wb + (0 * 3 + v) * 4096);
            const bf16x8 Af1 = *(const bf16x8*)(wb + (1 * 3 + v) * 4096);
            const bf16x8 Af2 = *(const bf16x8*)(wb + (2 * 3 + v) * 4096);
            #pragma unroll
            for (int g = 0; g < 2; ++g) {
                const int cc = g * 32 + n + v;
                const int koff = (kh * 16) ^ ((cc & 1) << 4);
                const unsigned char* cb = rb + cc * 32 + koff;
                const bf16x8 B0 = *(const bf16x8*)(cb + (2 * rp + 0) * (NCOL * 32));
                const bf16x8 B1 = *(const bf16x8*)(cb + (2 * rp + 1) * (NCOL * 32));
                const bf16x8 B2 = *(const bf16x8*)(cb + (2 * rp + 2) * (NCOL * 32));
                const bf16x8 B3 = *(const bf16x8*)(cb + (2 * rp + 3) * (NCOL * 32));
                acc[0][g] = __builtin_amdgcn_mfma_f32_32x32x16_bf16(Af0, B0, acc[0][g], 0, 0, 0);
                acc[1][g] = __builtin_amdgcn_mfma_f32_32x32x16_bf16(Af0, B1, acc[1][g], 0, 0, 0);
                acc[0][g] = __builtin_amdgcn_mfma_f32_32x32x16_bf16(Af1, B1, acc[0][g], 0, 0, 0);
                acc[1][g] = __builtin_amdgcn_mfma_f32_32x32x16_bf16(Af1, B2, acc[1][g], 0, 0, 0);
                acc[0][g] = __builtin_amdgcn_mfma_f32_32x32x16_bf16(Af2, B2, acc[0][g], 0, 0, 0);
                acc[1][g] = __builtin_amdgcn_mfma_f32_32x32x16_bf16(Af2, B3, acc[1][g], 0, 0, 0);
            }
        }
    };

    LOADS(0); WRITE(0); __syncthreads();
    #pragma unroll 1
    for (int c = 0; c < 4; ++c) {
        if (c < 3) LOADS(c + 1);
        COMPUTE(c);
        if (c < 3) WRITE(c + 1);
        __syncthreads();
    }
    #pragma unroll
    for (int rs = 0; rs < 2; ++rs) {
        const int h = h0 + 2 * rp + rs;
        #pragma unroll
        for (int g = 0; g < 2; ++g) {
            float* op = out + ((size_t)(b * CO + cohalf * 32) * HH + h) * WW + w0 + g * 32 + n;
            #pragma unroll
            for (int reg = 0; reg < 16; ++reg) {
                const int m = (reg & 3) + 8 * (reg >> 2) + 4 * kh;
                op[(size_t)m * (HH * WW)] = acc[rs][g][reg];
            }
        }
    }
}

// ===========================================================================
extern "C" void kernel_launch(void* const* d_in, const int* in_sizes, int n_in,
                              void* d_out, int out_size, void* d_ws, size_t ws_size,
                              hipStream_t stream) {
    const float* x        = (const float*)d_in[0];
    const float* prep_w   = (const float*)d_in[1];
    const float* bn_g     = (const float*)d_in[2];
    const float* bn_b     = (const float*)d_in[3];
    const float* bn_m     = (const float*)d_in[4];
    const float* bn_v     = (const float*)d_in[5];
    const float* fc_sp_w  = (const float*)d_in[6];
    const float* fc_sp_b  = (const float*)d_in[7];
    const float* fc_ch_w  = (const float*)d_in[8];
    const float* fc_ch_b  = (const float*)d_in[9];
    const float* fc_f_w   = (const float*)d_in[10];
    const float* fc_f_b   = (const float*)d_in[11];
    const float* fc_k_w   = (const float*)d_in[12];
    const float* fc_k_b   = (const float*)d_in[13];
    const float* kernels  = (const float*)d_in[14];
    float* out = (float*)d_out;
    float* ws  = (float*)d_ws;

    float* pooled = ws + WS_POOLED;
    float* cha    = ws + WS_CHA;
    float* fa     = ws + WS_FA;
    float* ka     = ws + WS_KA;
    float* sp     = ws + WS_SP;

    if (ws_size >= WS_NEED_F * sizeof(float)) {
        // ---- new path: NHWC bf16 + LDS-free MFMA conv ----
        float* partial = ws + WS_PART;
        unsigned short* w2t = (unsigned short*)(ws + WS_W2T_N);
        unsigned short* xt  = (unsigned short*)(ws + WS_XT);

        convert_pool<<<dim3(HH, NB), 256, 0, stream>>>(x, xt, partial);
        pool2_kernel<<<8, 256, 0, stream>>>(partial, pooled);
        attn2_kernel<<<1, 512, 0, stream>>>(pooled, prep_w, bn_g, bn_b, bn_m, bn_v,
                                            fc_sp_w, fc_sp_b, fc_ch_w, fc_ch_b,
                                            fc_f_w, fc_f_b, fc_k_w, fc_k_b,
                                            sp, cha, fa, ka, 1.f / (HH * WW));
        w2t_kernel<<<(NB * 9 * CO * CI) / 256, 256, 0, stream>>>(kernels, sp, cha, fa, ka, w2t);
        conv_mfma3<<<2048, 256, 0, stream>>>(xt, w2t, out);
    } else {
        // ---- fallback: r3 path ----
        unsigned short* w2t = (unsigned short*)(ws + WS_W2T_F);
        pool_kernel<<<NB * CI, 256, 0, stream>>>(x, pooled);
        attn2_kernel<<<1, 512, 0, stream>>>(pooled, prep_w, bn_g, bn_b, bn_m, bn_v,
                                            fc_sp_w, fc_sp_b, fc_ch_w, fc_ch_b,
                                            fc_f_w, fc_f_b, fc_k_w, fc_k_b,
                                            sp, cha, fa, ka, 1.f);
        w2t_kernel<<<(NB * 9 * CO * CI) / 256, 256, 0, stream>>>(kernels, sp, cha, fa, ka, w2t);
        dim3 grid(WW / 64, HH / 8, NB);
        conv_mfma2<<<grid, 512, 0, stream>>>(x, w2t, out);
    }
}